// Round 4
// baseline (399.946 us; speedup 1.0000x reference)
//
#include <hip/hip_runtime.h>
#include <stdint.h>
#include <math.h>

#define N_NODES   100000
#define N_EDGES   1600000
#define NFEAT     100
#define HIDDEN    32
#define OUTC      2

#define NB_SCAN   391   // ceil(100000/256)

// ---------------------------------------------------------------------------
// JAX threefry2x32, key=(0,42), partitionable scheme: bits(f) = o0^o1 of
// threefry2x32((0,42),(0,f)); uniform = bitcast((bits>>9)|0x3f800000)-1 < 0.8
// ---------------------------------------------------------------------------
__device__ __forceinline__ uint32_t rotl32(uint32_t x, int r) {
    return (x << r) | (x >> (32 - r));
}

__device__ __forceinline__ uint32_t threefry_bits(uint32_t f) {
    const uint32_t ks0 = 0u;
    const uint32_t ks1 = 42u;
    const uint32_t ks2 = 0x1BD11BDAu ^ 0u ^ 42u;
    uint32_t x0 = 0u + ks0;
    uint32_t x1 = f  + ks1;
#define TF_ROUND(r) { x0 += x1; x1 = rotl32(x1, (r)); x1 ^= x0; }
    TF_ROUND(13) TF_ROUND(15) TF_ROUND(26) TF_ROUND(6)
    x0 += ks1; x1 += ks2 + 1u;
    TF_ROUND(17) TF_ROUND(29) TF_ROUND(16) TF_ROUND(24)
    x0 += ks2; x1 += ks0 + 2u;
    TF_ROUND(13) TF_ROUND(15) TF_ROUND(26) TF_ROUND(6)
    x0 += ks0; x1 += ks1 + 3u;
    TF_ROUND(17) TF_ROUND(29) TF_ROUND(16) TF_ROUND(24)
    x0 += ks1; x1 += ks2 + 4u;
    TF_ROUND(13) TF_ROUND(15) TF_ROUND(26) TF_ROUND(6)
    x0 += ks2; x1 += ks0 + 5u;
#undef TF_ROUND
    return x0 ^ x1;
}

__device__ __forceinline__ bool dropout_keep(uint32_t f) {
    uint32_t bits = threefry_bits(f);
    float u = __uint_as_float((bits >> 9) | 0x3f800000u) - 1.0f;
    return u < 0.8f;
}

// ---------------------------------------------------------------------------
// 1. Degree histogram over dst (fire-and-forget int atomics)
// ---------------------------------------------------------------------------
__global__ __launch_bounds__(256) void k_deg(const int* __restrict__ dst,
                                             int* __restrict__ cnt) {
    int e = blockIdx.x * 256 + threadIdx.x;
    if (e < N_EDGES) atomicAdd(&cnt[dst[e]], 1);
}

// ---------------------------------------------------------------------------
// 2a. Per-block scan of cnt -> block-local exclusive prefix + block sums
// ---------------------------------------------------------------------------
__global__ __launch_bounds__(256) void k_scan1(const int* __restrict__ cnt,
                                               int* __restrict__ rowptr,
                                               int* __restrict__ bsum,
                                               float* __restrict__ dinv) {
    __shared__ int lds[256];
    const int t = threadIdx.x;
    const int i = blockIdx.x * 256 + t;
    int c = (i < N_NODES) ? cnt[i] : 0;
    lds[t] = c;
    __syncthreads();
#pragma unroll
    for (int off = 1; off < 256; off <<= 1) {
        int v = (t >= off) ? lds[t - off] : 0;
        __syncthreads();
        lds[t] += v;
        __syncthreads();
    }
    if (i < N_NODES) {
        rowptr[i] = lds[t] - c;
        dinv[i] = rsqrtf((float)(c + 1));
    }
    if (t == 255) bsum[blockIdx.x] = lds[255];
}

// ---------------------------------------------------------------------------
// 2b. Scan of the 391 block sums (single block)
// ---------------------------------------------------------------------------
__global__ __launch_bounds__(512) void k_scan2(const int* __restrict__ bsum,
                                               int* __restrict__ boff,
                                               int* __restrict__ rowptr) {
    __shared__ int lds[512];
    const int t = threadIdx.x;
    int v = (t < NB_SCAN) ? bsum[t] : 0;
    lds[t] = v;
    __syncthreads();
#pragma unroll
    for (int off = 1; off < 512; off <<= 1) {
        int u = (t >= off) ? lds[t - off] : 0;
        __syncthreads();
        lds[t] += u;
        __syncthreads();
    }
    if (t < NB_SCAN) boff[t] = lds[t] - v;
    if (t == 0) rowptr[N_NODES] = N_EDGES;
}

// ---------------------------------------------------------------------------
// 2c. Propagate block offsets; ALSO seed fill cursors with final rowptr so
//     k_scatter needs only ONE random access (the atomic) per edge.
// ---------------------------------------------------------------------------
__global__ __launch_bounds__(256) void k_scan3(int* __restrict__ rowptr,
                                               const int* __restrict__ boff,
                                               int* __restrict__ fill) {
    int i = blockIdx.x * 256 + threadIdx.x;
    if (i < N_NODES) {
        int r = rowptr[i] + boff[blockIdx.x];
        rowptr[i] = r;
        fill[i] = r;
    }
}

// ---------------------------------------------------------------------------
// 3. Scatter edges into CSR order: pos = atomicAdd(fill[d], 1)
// ---------------------------------------------------------------------------
__global__ __launch_bounds__(256) void k_scatter(const int* __restrict__ src,
                                                 const int* __restrict__ dst,
                                                 int* __restrict__ fill,
                                                 int* __restrict__ csr_src) {
    int e = blockIdx.x * 256 + threadIdx.x;
    if (e >= N_EDGES) return;
    int pos = atomicAdd(&fill[dst[e]], 1);
    csr_src[pos] = src[e];
}

// ---------------------------------------------------------------------------
// 4. h0s = (x @ W1) * dinv[row]   (pre-scaled by source norm)
// ---------------------------------------------------------------------------
__global__ __launch_bounds__(256) void k_gemm1(const float* __restrict__ x,
                                               const float* __restrict__ W1,
                                               const float* __restrict__ dinv,
                                               float* __restrict__ h0s) {
    __shared__ __align__(16) float w1s[NFEAT * HIDDEN];   // 3200 floats
    __shared__ __align__(16) float xs[8 * NFEAT];         // 800 floats
    const int tid = threadIdx.x;
    // W1: 800 float4s
    for (int i = tid; i < NFEAT * HIDDEN / 4; i += 256)
        ((float4*)w1s)[i] = ((const float4*)W1)[i];
    const int row0 = blockIdx.x * 8;
    const float4* xb = (const float4*)(x + (size_t)row0 * NFEAT);  // 800 floats = 200 float4
    if (tid < 200) ((float4*)xs)[tid] = xb[tid];
    __syncthreads();
    const int r = tid >> 5, c = tid & 31;
    float acc = 0.0f;
#pragma unroll 4
    for (int k = 0; k < NFEAT; ++k)
        acc = fmaf(xs[r * NFEAT + k], w1s[k * HIDDEN + c], acc);
    int row = row0 + r;
    h0s[(size_t)row * HIDDEN + c] = acc * dinv[row];
}

// ---------------------------------------------------------------------------
// 5. Layer 1: CSR aggregation of pre-scaled h0s + b1 + ReLU + dropout + @W2,
//    epilogue pre-scales h2 by dinv[n]. 32 lanes per node.
// ---------------------------------------------------------------------------
__global__ __launch_bounds__(256) void k_layer1(const int* __restrict__ rowptr,
                                                const int* __restrict__ csr_src,
                                                const float* __restrict__ dinv,
                                                const float* __restrict__ h0s,
                                                const float* __restrict__ b1,
                                                const float* __restrict__ W2,
                                                float* __restrict__ h2s) {
    int t = blockIdx.x * 256 + threadIdx.x;
    int n = t >> 5;
    int c = t & 31;
    if (n >= N_NODES) return;
    float acc = h0s[(size_t)n * HIDDEN + c];  // self loop (pre-scaled)
    int beg = rowptr[n], end = rowptr[n + 1];
    for (int j = beg; j < end; ++j) {
        int s = csr_src[j];
        acc += h0s[(size_t)s * HIDDEN + c];
    }
    float din = dinv[n];
    float v = fmaxf(fmaf(acc, din, b1[c]), 0.0f);
    v = dropout_keep((uint32_t)(n * HIDDEN + c)) ? v * 1.25f : 0.0f;
    float p0 = v * W2[c * 2 + 0];
    float p1 = v * W2[c * 2 + 1];
#pragma unroll
    for (int m = 16; m >= 1; m >>= 1) {
        p0 += __shfl_xor(p0, m);
        p1 += __shfl_xor(p1, m);
    }
    if (c == 0) {
        float2* o = (float2*)(h2s + (size_t)n * 2);
        *o = make_float2(p0 * din, p1 * din);
    }
}

// ---------------------------------------------------------------------------
// 6. Layer 2: CSR aggregation of pre-scaled h2s + b2 + log_softmax.
//    8 lanes per node striding the row (coalesced csr reads, 8 gathers in
//    flight).
// ---------------------------------------------------------------------------
__global__ __launch_bounds__(256) void k_layer2(const int* __restrict__ rowptr,
                                                const int* __restrict__ csr_src,
                                                const float* __restrict__ dinv,
                                                const float* __restrict__ h2s,
                                                const float* __restrict__ b2,
                                                float* __restrict__ out) {
    int t = blockIdx.x * 256 + threadIdx.x;
    int n = t >> 3;
    int l = t & 7;
    if (n >= N_NODES) return;
    float acc0 = 0.0f, acc1 = 0.0f;
    if (l == 0) {  // self loop (pre-scaled)
        float2 hn = ((const float2*)h2s)[n];
        acc0 = hn.x; acc1 = hn.y;
    }
    int beg = rowptr[n], end = rowptr[n + 1];
    for (int j = beg + l; j < end; j += 8) {
        float2 hs = ((const float2*)h2s)[csr_src[j]];
        acc0 += hs.x; acc1 += hs.y;
    }
#pragma unroll
    for (int m = 4; m >= 1; m >>= 1) {
        acc0 += __shfl_xor(acc0, m);
        acc1 += __shfl_xor(acc1, m);
    }
    if (l == 0) {
        float din = dinv[n];
        float l0 = fmaf(acc0, din, b2[0]);
        float l1 = fmaf(acc1, din, b2[1]);
        float m = fmaxf(l0, l1);
        float lse = m + logf(expf(l0 - m) + expf(l1 - m));
        float2* o = (float2*)(out + (size_t)n * 2);
        *o = make_float2(l0 - lse, l1 - lse);
    }
}

// ---------------------------------------------------------------------------
// Launch
// ---------------------------------------------------------------------------
static inline size_t align_up(size_t x) { return (x + 255) & ~(size_t)255; }

extern "C" void kernel_launch(void* const* d_in, const int* in_sizes, int n_in,
                              void* d_out, int out_size, void* d_ws, size_t ws_size,
                              hipStream_t stream) {
    (void)n_in; (void)in_sizes; (void)out_size; (void)ws_size;

    const float* x  = (const float*)d_in[0];
    const int*   ei = (const int*)d_in[1];
    const float* W1 = (const float*)d_in[2];
    const float* b1 = (const float*)d_in[3];
    const float* W2 = (const float*)d_in[4];
    const float* b2 = (const float*)d_in[5];
    float* out = (float*)d_out;

    const int* src = ei;
    const int* dst = ei + N_EDGES;

    char* w = (char*)d_ws;
    size_t off = 0;
    int*   cnt     = (int*)(w + off);   off += align_up((size_t)N_NODES * 4);
    int*   fill    = (int*)(w + off);   off += align_up((size_t)N_NODES * 4);
    int*   rowptr  = (int*)(w + off);   off += align_up((size_t)(N_NODES + 1) * 4);
    float* dinv    = (float*)(w + off); off += align_up((size_t)N_NODES * 4);
    int*   bsum    = (int*)(w + off);   off += align_up((size_t)NB_SCAN * 4);
    int*   boff    = (int*)(w + off);   off += align_up((size_t)NB_SCAN * 4);
    int*   csr_src = (int*)(w + off);   off += align_up((size_t)N_EDGES * 4);
    float* h0s     = (float*)(w + off); off += align_up((size_t)N_NODES * HIDDEN * 4);
    float* h2s     = (float*)(w + off); off += align_up((size_t)N_NODES * OUTC * 4);

    hipMemsetAsync(cnt, 0, (size_t)N_NODES * 4, stream);

    const int B = 256;
    k_deg    <<<(N_EDGES + B - 1) / B, B, 0, stream>>>(dst, cnt);
    k_scan1  <<<NB_SCAN, B, 0, stream>>>(cnt, rowptr, bsum, dinv);
    k_scan2  <<<1, 512, 0, stream>>>(bsum, boff, rowptr);
    k_scan3  <<<NB_SCAN, B, 0, stream>>>(rowptr, boff, fill);
    k_scatter<<<(N_EDGES + B - 1) / B, B, 0, stream>>>(src, dst, fill, csr_src);
    k_gemm1  <<<N_NODES / 8, B, 0, stream>>>(x, W1, dinv, h0s);
    k_layer1 <<<(N_NODES * HIDDEN + B - 1) / B, B, 0, stream>>>(rowptr, csr_src, dinv, h0s, b1, W2, h2s);
    k_layer2 <<<(N_NODES * 8 + B - 1) / B, B, 0, stream>>>(rowptr, csr_src, dinv, h2s, b2, out);
}